// Round 15
// baseline (631.757 us; speedup 1.0000x reference)
//
#include <hip/hip_runtime.h>

#define NN 2048
#define KK 20
#define BB 16
#define TPRE 1.79989f   // relu(A) prefilter; key>=1.8 => v>=1.8-1e-4 (noise<1)
#define CAP 128         // candidate capacity per wave (mean ~74, 6.4 sigma)

typedef __attribute__((ext_vector_type(4))) float f32x4;
typedef unsigned long long u64;

// ---------------------------------------------------------------------------
// Kernel 1 (v16): per-row exact top-K, FOUR rows per wave, straight-line
// load rotation. v15 (2 rows, both bursts up front) showed the cap is load
// duty cycle: all loads issue in the first ~900cy of a ~4000cy lifetime.
// v16 keeps a burst in flight across ~80% of the wave: two named float4[8]
// arrays, each reused for two rows (dead-range reuse, no loop, no
// conditional reload -> no scratch demotion, per v13's lesson):
//   load a(r0); load b(r1); compact a; load a(r2); select r0;
//   compact b; load b(r3); select r1; compact a; select r2;
//   compact b; select r3.
// Internals = v12 (measured best):
//  - ballot-prefix compaction of v-candidates (v = relu(A) >= TPRE)
//  - noise-free fast path: if gap between K-th and (K+1)-th candidate v
//    >= 1.01e-4, top-K set by key == top-K set by v (noise*1e-4 < 1e-4
//    can't reorder across the gap; downstream consumes only the index SET)
//  - rare (~1%) pass B: gather noise, re-rank by full key (exact)
//  - rank-based selection on packed u64:
//      packed = (float_bits(x) << 32) | (NN-1-idx)  (x>0 => monotonic)
//      rank(c) = #{y : packed_y > packed_c}; selected iff rank<K; slot=rank
//  - slim EMIT: 2 stores + fire-and-forget colsum atomic
// Fallback for cnt<K or cnt>CAP (P ~ 1e-10/row): full-row re-read bisection.
// ---------------------------------------------------------------------------

__device__ __forceinline__ int compact_row(
    const float4 (&a)[8], int lane, int wv, u64 ltm,
    float (&cand_val)[4][CAP], int (&cand_idx)[4][CAP])
{
    int cnt = 0;
#pragma unroll
    for (int c = 0; c < 8; ++c) {
        float av[4] = {a[c].x, a[c].y, a[c].z, a[c].w};
#pragma unroll
        for (int q = 0; q < 4; ++q) {
            float v = fmaxf(av[q], 0.f);
            bool p = v >= TPRE;
            u64 m = __ballot(p);
            if (p) {
                int pos = cnt + __popcll(m & ltm);
                if (pos < CAP) {
                    cand_val[wv][pos] = v;
                    cand_idx[wv][pos] = c * 256 + lane * 4 + q;
                }
            }
            cnt += __popcll(m);
        }
    }
    return cnt;
}

__device__ __forceinline__ void row_select(
    int lane, int wv, int cnt, int row,
    const float* __restrict__ Ar, const float* __restrict__ Nr,
    int* __restrict__ sel_idx, float* __restrict__ sel_val,
    float* __restrict__ colsum, u64 ltm,
    u64 (&cand_pk)[4][CAP + 8], float (&cand_val)[4][CAP],
    int (&cand_idx)[4][CAP], float (&bnd)[4][2],
    int (&tie_idx)[4][64], int (&tie_cnt)[4])
{
    const int colbase = row & ~(NN - 1);
    int*   si = sel_idx + (size_t)row * KK;
    float* sv = sel_val + (size_t)row * KK;

#define EMIT(POS, IDX, V)                                                      \
    do {                                                                       \
        int _p = (POS); int _i = (IDX); float _v = (V);                        \
        si[_p] = _i; sv[_p] = _v;                                              \
        atomicAdd(&colsum[colbase + _i], _v);                                  \
    } while (0)

#define PACK(X, IDX)                                                           \
    ((((u64)__float_as_uint(X)) << 32) | (unsigned)(NN - 1 - (IDX)))

    if (cnt >= KK && cnt <= CAP) {
        int   i0 = (lane      < cnt) ? cand_idx[wv][lane]      : -1;
        int   i1 = (lane + 64 < cnt) ? cand_idx[wv][lane + 64] : -1;
        float v0 = (i0 >= 0) ? cand_val[wv][lane]      : 0.f;
        float v1 = (i1 >= 0) ? cand_val[wv][lane + 64] : 0.f;

        const int nIter = (cnt + 3) & ~3;

        auto rankscan = [&](u64 p0, u64 p1, int& r0, int& r1) {
            r0 = 0; r1 = 0;
            for (int j = 0; j < nIter; j += 4) {
                u64 b[4];
#pragma unroll
                for (int u = 0; u < 4; ++u) b[u] = cand_pk[wv][j + u];
#pragma unroll
                for (int u = 0; u < 4; ++u) {
                    r0 += (b[u] > p0);
                    r1 += (b[u] > p1);
                }
            }
        };

        // ---- Pass A: rank by packed (v, idx) — NO noise reads -------------
        u64 pk0 = ~0ull, pk1 = ~0ull;
        if (i0 >= 0) { pk0 = PACK(v0, i0); cand_pk[wv][lane]      = pk0; }
        if (i1 >= 0) { pk1 = PACK(v1, i1); cand_pk[wv][lane + 64] = pk1; }
        if (lane < nIter - cnt) cand_pk[wv][cnt + lane] = 0ull;  // sentinel

        int r0, r1;
        rankscan(pk0, pk1, r0, r1);

        // boundary values vK (rank K-1) and vK1 (rank K); ranks unique
        if (i0 >= 0) {
            if (r0 == KK - 1) bnd[wv][0] = v0;
            if (r0 == KK)     bnd[wv][1] = v0;
        }
        if (i1 >= 0) {
            if (r1 == KK - 1) bnd[wv][0] = v1;
            if (r1 == KK)     bnd[wv][1] = v1;
        }

        bool gapok = (cnt == KK) || (bnd[wv][0] - bnd[wv][1] > 1.01e-4f);

        if (!gapok) {
            // ---- Pass B (rare ~1%): gather noise, re-rank by full key -----
            if (i0 >= 0) {
                float k0 = fmaf(Nr[i0], 1e-4f, v0);
                pk0 = PACK(k0, i0); cand_pk[wv][lane] = pk0;
            }
            if (i1 >= 0) {
                float k1 = fmaf(Nr[i1], 1e-4f, v1);
                pk1 = PACK(k1, i1); cand_pk[wv][lane + 64] = pk1;
            }
            rankscan(pk0, pk1, r0, r1);
        }

        if (i0 >= 0 && r0 < KK) EMIT(r0, i0, v0);
        if (i1 >= 0 && r1 < KK) EMIT(r1, i1, v1);
        return;
    }

    // ---- Fallback (cold, exact): full-row re-read bisection ---------------
    {
        unsigned lo = 0u, hi = 0x7F800000u;
        unsigned tb = 0u;
        bool exact = false;
        while (hi - lo > 1u) {
            unsigned mid = (lo + hi) >> 1;
            float tm = __uint_as_float(mid);
            int c = 0;
            for (int j = 0; j < 32; ++j) {
                float av = Ar[j * 64 + lane];
                float nv = Nr[j * 64 + lane];
                float k = fmaf(nv, 1e-4f, fmaxf(av, 0.f));
                c += __popcll(__ballot(k >= tm));
            }
            if (c == KK) { tb = mid; exact = true; break; }
            if (c > KK) lo = mid; else hi = mid;
        }
        if (exact) {
            float t = __uint_as_float(tb);
            int run = 0;
            for (int j = 0; j < 32; ++j) {
                float av = Ar[j * 64 + lane];
                float nv = Nr[j * 64 + lane];
                float v = fmaxf(av, 0.f);
                float k = fmaf(nv, 1e-4f, v);
                bool p = k >= t;
                u64 m = __ballot(p);
                if (p) EMIT(run + __popcll(m & ltm), j * 64 + lane, v);
                run += __popcll(m);
            }
        } else {
            // Exact tie at the K/K+1 boundary (lax.top_k semantics).
            float t1 = __uint_as_float(lo);
            int run = 0;
            for (int j = 0; j < 32; ++j) {
                float av = Ar[j * 64 + lane];
                float nv = Nr[j * 64 + lane];
                float v = fmaxf(av, 0.f);
                float k = fmaf(nv, 1e-4f, v);
                bool p = k > t1;
                u64 m = __ballot(p);
                if (p) EMIT(run + __popcll(m & ltm), j * 64 + lane, v);
                run += __popcll(m);
            }
            if (lane == 0) tie_cnt[wv] = 0;
            for (int j = 0; j < 32; ++j) {
                float av = Ar[j * 64 + lane];
                float nv = Nr[j * 64 + lane];
                float k = fmaf(nv, 1e-4f, fmaxf(av, 0.f));
                if (k == t1) {
                    int p = atomicAdd(&tie_cnt[wv], 1);
                    if (p < 64) tie_idx[wv][p] = j * 64 + lane;
                }
            }
            if (lane == 0) {
                int n = tie_cnt[wv]; if (n > 64) n = 64;
                int need = KK - run;
                for (int s = 0; s < need; ++s) {
                    int bq = 0, bidx = 0x7fffffff;
                    for (int q = 0; q < n; ++q) {
                        int v = tie_idx[wv][q];
                        if (v < bidx) { bidx = v; bq = q; }
                    }
                    tie_idx[wv][bq] = 0x7fffffff;
                    float v = fmaxf(Ar[bidx], 0.f);
                    EMIT(run + s, bidx, v);
                }
            }
        }
    }
#undef EMIT
#undef PACK
}

__device__ __forceinline__ void load_burst(
    float4 (&dst)[8], const float* __restrict__ src, int lane)
{
#pragma unroll
    for (int c = 0; c < 8; ++c)
        dst[c] = *(const float4*)(src + c * 256 + lane * 4);
}

__global__ __launch_bounds__(256, 4) void topk_kernel(
    const float* __restrict__ A, const float* __restrict__ noise,
    int* __restrict__ sel_idx, float* __restrict__ sel_val,
    float* __restrict__ colsum)
{
    __shared__ u64   cand_pk[4][CAP + 8];
    __shared__ float cand_val[4][CAP];
    __shared__ int   cand_idx[4][CAP];
    __shared__ float bnd[4][2];
    __shared__ int   tie_idx[4][64];
    __shared__ int   tie_cnt[4];

    const int lane = threadIdx.x & 63;
    const int wv   = threadIdx.x >> 6;
    const u64 ltm  = (1ull << lane) - 1ull;

    const int row0 = blockIdx.x * 16 + wv;         // 4 rows per wave
    const int row1 = row0 + 4;
    const int row2 = row0 + 8;
    const int row3 = row0 + 12;
    const float* Ar0 = A     + (size_t)row0 * NN;
    const float* Ar1 = A     + (size_t)row1 * NN;
    const float* Ar2 = A     + (size_t)row2 * NN;
    const float* Ar3 = A     + (size_t)row3 * NN;
    const float* Nr0 = noise + (size_t)row0 * NN;
    const float* Nr1 = noise + (size_t)row1 * NN;
    const float* Nr2 = noise + (size_t)row2 * NN;
    const float* Nr3 = noise + (size_t)row3 * NN;

    float4 a[8], b[8];

    // ---- rotation: a burst is in flight during nearly every phase ---------
    load_burst(a, Ar0, lane);                      // r0 in flight
    load_burst(b, Ar1, lane);                      // r1 in flight
    int cnt0 = compact_row(a, lane, wv, ltm, cand_val, cand_idx);  // waits r0
    load_burst(a, Ar2, lane);                      // r2 in flight (a reused)
    row_select(lane, wv, cnt0, row0, Ar0, Nr0, sel_idx, sel_val, colsum, ltm,
               cand_pk, cand_val, cand_idx, bnd, tie_idx, tie_cnt);
    int cnt1 = compact_row(b, lane, wv, ltm, cand_val, cand_idx);  // waits r1
    load_burst(b, Ar3, lane);                      // r3 in flight (b reused)
    row_select(lane, wv, cnt1, row1, Ar1, Nr1, sel_idx, sel_val, colsum, ltm,
               cand_pk, cand_val, cand_idx, bnd, tie_idx, tie_cnt);
    int cnt2 = compact_row(a, lane, wv, ltm, cand_val, cand_idx);  // waits r2
    row_select(lane, wv, cnt2, row2, Ar2, Nr2, sel_idx, sel_val, colsum, ltm,
               cand_pk, cand_val, cand_idx, bnd, tie_idx, tie_cnt);
    int cnt3 = compact_row(b, lane, wv, ltm, cand_val, cand_idx);  // waits r3
    row_select(lane, wv, cnt3, row3, Ar3, Nr3, sel_idx, sel_val, colsum, ltm,
               cand_pk, cand_val, cand_idx, bnd, tie_idx, tie_cnt);
}

// ---------------------------------------------------------------------------
// Kernel 2: dinv = (1 + 0.5*(rowsum + colsum))^-1/2.
// ---------------------------------------------------------------------------
__global__ __launch_bounds__(256) void dinv_kernel(
    const float* __restrict__ sel_val, const float* __restrict__ colsum,
    float* __restrict__ dinv)
{
    int r = blockIdx.x * 256 + threadIdx.x;        // 0 .. 32767
    const float* svp = sel_val + (size_t)r * KK;
    float rs = 0.f;
#pragma unroll
    for (int k = 0; k < KK; ++k) rs += svp[k];
    float d = 1.0f + 0.5f * (rs + colsum[r]);
    dinv[r] = 1.0f / sqrtf(d);                     // d >= 1 always
}

// ---------------------------------------------------------------------------
// Kernel 3 (v6 structure — measured best): global scatter onto the
// memset-zeroed output (driver fill leaves out cache-warm; NT-store zeroing
// regressed scatter in v8 — keep the driver memset). One thread per (row,k),
// two fire-and-forget atomicAdds: out[r][j] += w, out[j][r] += w,
// w = 0.5*v*d_r*d_j; plus one thread per row for the diagonal d_r^2.
// ---------------------------------------------------------------------------
__global__ __launch_bounds__(256) void scatter_kernel(
    const int* __restrict__ sel_idx, const float* __restrict__ sel_val,
    const float* __restrict__ dinv, float* __restrict__ out)
{
    int tid = blockIdx.x * 256 + threadIdx.x;      // 0 .. 32768*21-1
    int r = tid / 21;                              // magic-mul division
    int s = tid - r * 21;
    const int colbase = r & ~(NN - 1);
    const int i = r & (NN - 1);
    float dr = dinv[r];

    if (s == 20) {
        atomicAdd(&out[(size_t)r * NN + i], dr * dr);     // (A+I) diagonal
    } else {
        int   j = sel_idx[(size_t)r * KK + s];
        float v = sel_val[(size_t)r * KK + s];
        float w = 0.5f * v * dr * dinv[colbase + j];
        atomicAdd(&out[(size_t)r * NN + j], w);
        atomicAdd(&out[(size_t)(colbase + j) * NN + i], w);
    }
}

// ---------------------------------------------------------------------------
extern "C" void kernel_launch(void* const* d_in, const int* in_sizes, int n_in,
                              void* d_out, int out_size, void* d_ws, size_t ws_size,
                              hipStream_t stream)
{
    const float* A     = (const float*)d_in[0];
    const float* noise = (const float*)d_in[1];
    float* out = (float*)d_out;
    char*  ws  = (char*)d_ws;

    const int rows = BB * NN;                      // 32768
    // workspace layout (~5.5 MB total)
    size_t off = 0;
    int*   sel_idx = (int*)(ws + off);            off += (size_t)rows * KK * 4;   // 2.62 MB
    float* sel_val = (float*)(ws + off);          off += (size_t)rows * KK * 4;   // 2.62 MB
    float* colsum  = (float*)(ws + off);          off += (size_t)rows * 4;        // 128 KB
    float* dinv    = (float*)(ws + off);                                          // 128 KB

    hipMemsetAsync(out, 0, (size_t)out_size, stream);
    hipMemsetAsync(colsum, 0, rows * sizeof(float), stream);

    topk_kernel<<<rows / 16, 256, 0, stream>>>(A, noise, sel_idx, sel_val, colsum);
    dinv_kernel<<<rows / 256, 256, 0, stream>>>(sel_val, colsum, dinv);
    scatter_kernel<<<rows * 21 / 256, 256, 0, stream>>>(sel_idx, sel_val, dinv, out);
}

// Round 16
// 582.830 us; speedup vs baseline: 1.0839x; 1.0839x over previous
//
#include <hip/hip_runtime.h>

#define NN 2048
#define KK 20
#define BB 16
#define TPRE 1.79989f   // relu(A) prefilter; key>=1.8 => v>=1.8-1e-4 (noise<1)
#define CAP 128         // candidate capacity per wave (mean ~74, 6.4 sigma)

typedef __attribute__((ext_vector_type(4))) float f32x4;
typedef unsigned long long u64;

// ---------------------------------------------------------------------------
// Kernel 1 (v15 — session best, 583.6us total): per-row exact top-K, TWO
// rows per wave, BOTH load bursts issued back-to-back (16 independent
// dwordx4 in flight per wave). v16's 4-row rotation regressed (-48us):
// keeping a[]/b[] live across row_select calls forced spill/serialization.
// This 2-row form is the measured optimum of the MLP family (v10-v16).
// Internals = v12 (measured best):
//  - ballot-prefix compaction of v-candidates (v = relu(A) >= TPRE)
//  - noise-free fast path: if gap between K-th and (K+1)-th candidate v
//    >= 1.01e-4, top-K set by key == top-K set by v (noise*1e-4 < 1e-4
//    can't reorder across the gap; downstream consumes only the index SET)
//  - rare (~1%) pass B: gather noise, re-rank by full key (exact)
//  - rank-based selection on packed u64:
//      packed = (float_bits(x) << 32) | (NN-1-idx)  (x>0 => monotonic)
//      rank(c) = #{y : packed_y > packed_c}; selected iff rank<K; slot=rank
//  - slim EMIT: 2 stores + fire-and-forget colsum atomic
// Fallback for cnt<K or cnt>CAP (P ~ 1e-10/row): full-row re-read bisection.
// ---------------------------------------------------------------------------

__device__ __forceinline__ int compact_row(
    const float4 (&a)[8], int lane, int wv, u64 ltm,
    float (&cand_val)[4][CAP], int (&cand_idx)[4][CAP])
{
    int cnt = 0;
#pragma unroll
    for (int c = 0; c < 8; ++c) {
        float av[4] = {a[c].x, a[c].y, a[c].z, a[c].w};
#pragma unroll
        for (int q = 0; q < 4; ++q) {
            float v = fmaxf(av[q], 0.f);
            bool p = v >= TPRE;
            u64 m = __ballot(p);
            if (p) {
                int pos = cnt + __popcll(m & ltm);
                if (pos < CAP) {
                    cand_val[wv][pos] = v;
                    cand_idx[wv][pos] = c * 256 + lane * 4 + q;
                }
            }
            cnt += __popcll(m);
        }
    }
    return cnt;
}

__device__ __forceinline__ void row_select(
    int lane, int wv, int cnt, int row,
    const float* __restrict__ Ar, const float* __restrict__ Nr,
    int* __restrict__ sel_idx, float* __restrict__ sel_val,
    float* __restrict__ colsum, u64 ltm,
    u64 (&cand_pk)[4][CAP + 8], float (&cand_val)[4][CAP],
    int (&cand_idx)[4][CAP], float (&bnd)[4][2],
    int (&tie_idx)[4][64], int (&tie_cnt)[4])
{
    const int colbase = row & ~(NN - 1);
    int*   si = sel_idx + (size_t)row * KK;
    float* sv = sel_val + (size_t)row * KK;

#define EMIT(POS, IDX, V)                                                      \
    do {                                                                       \
        int _p = (POS); int _i = (IDX); float _v = (V);                        \
        si[_p] = _i; sv[_p] = _v;                                              \
        atomicAdd(&colsum[colbase + _i], _v);                                  \
    } while (0)

#define PACK(X, IDX)                                                           \
    ((((u64)__float_as_uint(X)) << 32) | (unsigned)(NN - 1 - (IDX)))

    if (cnt >= KK && cnt <= CAP) {
        int   i0 = (lane      < cnt) ? cand_idx[wv][lane]      : -1;
        int   i1 = (lane + 64 < cnt) ? cand_idx[wv][lane + 64] : -1;
        float v0 = (i0 >= 0) ? cand_val[wv][lane]      : 0.f;
        float v1 = (i1 >= 0) ? cand_val[wv][lane + 64] : 0.f;

        const int nIter = (cnt + 3) & ~3;

        auto rankscan = [&](u64 p0, u64 p1, int& r0, int& r1) {
            r0 = 0; r1 = 0;
            for (int j = 0; j < nIter; j += 4) {
                u64 b[4];
#pragma unroll
                for (int u = 0; u < 4; ++u) b[u] = cand_pk[wv][j + u];
#pragma unroll
                for (int u = 0; u < 4; ++u) {
                    r0 += (b[u] > p0);
                    r1 += (b[u] > p1);
                }
            }
        };

        // ---- Pass A: rank by packed (v, idx) — NO noise reads -------------
        u64 pk0 = ~0ull, pk1 = ~0ull;
        if (i0 >= 0) { pk0 = PACK(v0, i0); cand_pk[wv][lane]      = pk0; }
        if (i1 >= 0) { pk1 = PACK(v1, i1); cand_pk[wv][lane + 64] = pk1; }
        if (lane < nIter - cnt) cand_pk[wv][cnt + lane] = 0ull;  // sentinel

        int r0, r1;
        rankscan(pk0, pk1, r0, r1);

        // boundary values vK (rank K-1) and vK1 (rank K); ranks unique
        if (i0 >= 0) {
            if (r0 == KK - 1) bnd[wv][0] = v0;
            if (r0 == KK)     bnd[wv][1] = v0;
        }
        if (i1 >= 0) {
            if (r1 == KK - 1) bnd[wv][0] = v1;
            if (r1 == KK)     bnd[wv][1] = v1;
        }

        bool gapok = (cnt == KK) || (bnd[wv][0] - bnd[wv][1] > 1.01e-4f);

        if (!gapok) {
            // ---- Pass B (rare ~1%): gather noise, re-rank by full key -----
            if (i0 >= 0) {
                float k0 = fmaf(Nr[i0], 1e-4f, v0);
                pk0 = PACK(k0, i0); cand_pk[wv][lane] = pk0;
            }
            if (i1 >= 0) {
                float k1 = fmaf(Nr[i1], 1e-4f, v1);
                pk1 = PACK(k1, i1); cand_pk[wv][lane + 64] = pk1;
            }
            rankscan(pk0, pk1, r0, r1);
        }

        if (i0 >= 0 && r0 < KK) EMIT(r0, i0, v0);
        if (i1 >= 0 && r1 < KK) EMIT(r1, i1, v1);
        return;
    }

    // ---- Fallback (cold, exact): full-row re-read bisection ---------------
    {
        unsigned lo = 0u, hi = 0x7F800000u;
        unsigned tb = 0u;
        bool exact = false;
        while (hi - lo > 1u) {
            unsigned mid = (lo + hi) >> 1;
            float tm = __uint_as_float(mid);
            int c = 0;
            for (int j = 0; j < 32; ++j) {
                float av = Ar[j * 64 + lane];
                float nv = Nr[j * 64 + lane];
                float k = fmaf(nv, 1e-4f, fmaxf(av, 0.f));
                c += __popcll(__ballot(k >= tm));
            }
            if (c == KK) { tb = mid; exact = true; break; }
            if (c > KK) lo = mid; else hi = mid;
        }
        if (exact) {
            float t = __uint_as_float(tb);
            int run = 0;
            for (int j = 0; j < 32; ++j) {
                float av = Ar[j * 64 + lane];
                float nv = Nr[j * 64 + lane];
                float v = fmaxf(av, 0.f);
                float k = fmaf(nv, 1e-4f, v);
                bool p = k >= t;
                u64 m = __ballot(p);
                if (p) EMIT(run + __popcll(m & ltm), j * 64 + lane, v);
                run += __popcll(m);
            }
        } else {
            // Exact tie at the K/K+1 boundary (lax.top_k semantics).
            float t1 = __uint_as_float(lo);
            int run = 0;
            for (int j = 0; j < 32; ++j) {
                float av = Ar[j * 64 + lane];
                float nv = Nr[j * 64 + lane];
                float v = fmaxf(av, 0.f);
                float k = fmaf(nv, 1e-4f, v);
                bool p = k > t1;
                u64 m = __ballot(p);
                if (p) EMIT(run + __popcll(m & ltm), j * 64 + lane, v);
                run += __popcll(m);
            }
            if (lane == 0) tie_cnt[wv] = 0;
            for (int j = 0; j < 32; ++j) {
                float av = Ar[j * 64 + lane];
                float nv = Nr[j * 64 + lane];
                float k = fmaf(nv, 1e-4f, fmaxf(av, 0.f));
                if (k == t1) {
                    int p = atomicAdd(&tie_cnt[wv], 1);
                    if (p < 64) tie_idx[wv][p] = j * 64 + lane;
                }
            }
            if (lane == 0) {
                int n = tie_cnt[wv]; if (n > 64) n = 64;
                int need = KK - run;
                for (int s = 0; s < need; ++s) {
                    int bq = 0, bidx = 0x7fffffff;
                    for (int q = 0; q < n; ++q) {
                        int v = tie_idx[wv][q];
                        if (v < bidx) { bidx = v; bq = q; }
                    }
                    tie_idx[wv][bq] = 0x7fffffff;
                    float v = fmaxf(Ar[bidx], 0.f);
                    EMIT(run + s, bidx, v);
                }
            }
        }
    }
#undef EMIT
#undef PACK
}

__global__ __launch_bounds__(256, 4) void topk_kernel(
    const float* __restrict__ A, const float* __restrict__ noise,
    int* __restrict__ sel_idx, float* __restrict__ sel_val,
    float* __restrict__ colsum)
{
    __shared__ u64   cand_pk[4][CAP + 8];
    __shared__ float cand_val[4][CAP];
    __shared__ int   cand_idx[4][CAP];
    __shared__ float bnd[4][2];
    __shared__ int   tie_idx[4][64];
    __shared__ int   tie_cnt[4];

    const int lane = threadIdx.x & 63;
    const int wv   = threadIdx.x >> 6;
    const u64 ltm  = (1ull << lane) - 1ull;

    const int row0 = blockIdx.x * 8 + wv;          // first row of this wave
    const int row1 = row0 + 4;                     // second row
    const float* Ar0 = A     + (size_t)row0 * NN;
    const float* Nr0 = noise + (size_t)row0 * NN;
    const float* Ar1 = A     + (size_t)row1 * NN;
    const float* Nr1 = noise + (size_t)row1 * NN;

    // ---- BOTH load bursts back-to-back: 16 independent dwordx4 in flight --
    float4 a[8];
#pragma unroll
    for (int c = 0; c < 8; ++c)
        a[c] = *(const float4*)(Ar0 + c * 256 + lane * 4);
    float4 b[8];
#pragma unroll
    for (int c = 0; c < 8; ++c)
        b[c] = *(const float4*)(Ar1 + c * 256 + lane * 4);

    // ---- row0: compact (waits only on a) + select (b still in flight) -----
    int cnt0 = compact_row(a, lane, wv, ltm, cand_val, cand_idx);
    row_select(lane, wv, cnt0, row0, Ar0, Nr0, sel_idx, sel_val, colsum, ltm,
               cand_pk, cand_val, cand_idx, bnd, tie_idx, tie_cnt);

    // ---- row1: compact + select -------------------------------------------
    int cnt1 = compact_row(b, lane, wv, ltm, cand_val, cand_idx);
    row_select(lane, wv, cnt1, row1, Ar1, Nr1, sel_idx, sel_val, colsum, ltm,
               cand_pk, cand_val, cand_idx, bnd, tie_idx, tie_cnt);
}

// ---------------------------------------------------------------------------
// Kernel 2: dinv = (1 + 0.5*(rowsum + colsum))^-1/2.
// ---------------------------------------------------------------------------
__global__ __launch_bounds__(256) void dinv_kernel(
    const float* __restrict__ sel_val, const float* __restrict__ colsum,
    float* __restrict__ dinv)
{
    int r = blockIdx.x * 256 + threadIdx.x;        // 0 .. 32767
    const float* svp = sel_val + (size_t)r * KK;
    float rs = 0.f;
#pragma unroll
    for (int k = 0; k < KK; ++k) rs += svp[k];
    float d = 1.0f + 0.5f * (rs + colsum[r]);
    dinv[r] = 1.0f / sqrtf(d);                     // d >= 1 always
}

// ---------------------------------------------------------------------------
// Kernel 3 (v6 structure — measured best): global scatter onto the
// memset-zeroed output (driver fill leaves out cache-warm; NT-store zeroing
// regressed scatter in v8 — keep the driver memset). One thread per (row,k),
// two fire-and-forget atomicAdds: out[r][j] += w, out[j][r] += w,
// w = 0.5*v*d_r*d_j; plus one thread per row for the diagonal d_r^2.
// ---------------------------------------------------------------------------
__global__ __launch_bounds__(256) void scatter_kernel(
    const int* __restrict__ sel_idx, const float* __restrict__ sel_val,
    const float* __restrict__ dinv, float* __restrict__ out)
{
    int tid = blockIdx.x * 256 + threadIdx.x;      // 0 .. 32768*21-1
    int r = tid / 21;                              // magic-mul division
    int s = tid - r * 21;
    const int colbase = r & ~(NN - 1);
    const int i = r & (NN - 1);
    float dr = dinv[r];

    if (s == 20) {
        atomicAdd(&out[(size_t)r * NN + i], dr * dr);     // (A+I) diagonal
    } else {
        int   j = sel_idx[(size_t)r * KK + s];
        float v = sel_val[(size_t)r * KK + s];
        float w = 0.5f * v * dr * dinv[colbase + j];
        atomicAdd(&out[(size_t)r * NN + j], w);
        atomicAdd(&out[(size_t)(colbase + j) * NN + i], w);
    }
}

// ---------------------------------------------------------------------------
extern "C" void kernel_launch(void* const* d_in, const int* in_sizes, int n_in,
                              void* d_out, int out_size, void* d_ws, size_t ws_size,
                              hipStream_t stream)
{
    const float* A     = (const float*)d_in[0];
    const float* noise = (const float*)d_in[1];
    float* out = (float*)d_out;
    char*  ws  = (char*)d_ws;

    const int rows = BB * NN;                      // 32768
    // workspace layout (~5.5 MB total)
    size_t off = 0;
    int*   sel_idx = (int*)(ws + off);            off += (size_t)rows * KK * 4;   // 2.62 MB
    float* sel_val = (float*)(ws + off);          off += (size_t)rows * KK * 4;   // 2.62 MB
    float* colsum  = (float*)(ws + off);          off += (size_t)rows * 4;        // 128 KB
    float* dinv    = (float*)(ws + off);                                          // 128 KB

    hipMemsetAsync(out, 0, (size_t)out_size, stream);
    hipMemsetAsync(colsum, 0, rows * sizeof(float), stream);

    topk_kernel<<<rows / 8, 256, 0, stream>>>(A, noise, sel_idx, sel_val, colsum);
    dinv_kernel<<<rows / 256, 256, 0, stream>>>(sel_val, colsum, dinv);
    scatter_kernel<<<rows * 21 / 256, 256, 0, stream>>>(sel_idx, sel_val, dinv, out);
}